// Round 8
// baseline (1174.704 us; speedup 1.0000x reference)
//
#include <hip/hip_runtime.h>
#include <math.h>

#define N 64
#define GS 68   // LDS row stride (floats); 272 B rows, b128-aligned, 8-way-max banking
#define MAX_ITER 5

__device__ __forceinline__ float rl(float x, int lane) {
    return __uint_as_float(__builtin_amdgcn_readlane(__float_as_uint(x), lane));
}

// One 64-thread wave per 64x64 SPD matrix — R7 structure (1166us, VALUBusy 77%)
// + phase-2 k-loop FULL UNROLL. Cross-round model (R2/R5/R6/R7): wall ~
// (instruction issue)/(resident waves); occupancy is LDS-capped at 9 blocks/CU
// so the remaining lever is instruction count. R7's k-loop pays per-step
// runtime-k overhead: rowk pointer setup, 8 runtime block predicates, VGPR
// ds_read addressing. With k compile-time (63 constant trips, #pragma unroll):
//   - vk/vk1 reads become ds_read_b128 zero-base + offset:imm (max 17104 <
//     64KB) -> zero address VALU;
//   - block predicates (j0+8>k) fold away at compile time;
//   - rl(betaS, k) takes a constant lane.
// ~35 instr/step x 315 steps ~ 10% of the issued stream. Identical ops in
// identical order -> bit-exact vs R7. qt[] stays cold/spilled by the RA
// (WRITE ~388MB) — measured cheapest parking vs LDS stash (R5) or fused
// registers (R6); its BW cost (~5% peak) hides behind 8-9 resident waves.
__global__ __launch_bounds__(64)
__attribute__((amdgpu_waves_per_eu(1, 2)))
void logm_kernel(const float* __restrict__ gin, float* __restrict__ gout) {
    __shared__ __align__(16) float G[N * GS];  // 17408 B -> 9 blocks/CU
    const int t = threadIdx.x;
    const long b = blockIdx.x;
    const float* __restrict__ in = gin + b * (long)(N * N);
    float* __restrict__ out = gout + b * (long)(N * N);

    float a[N], r[N], qt[N];

    #pragma unroll
    for (int i = 0; i < N; ++i) a[i] = in[i * N + t];
    #pragma unroll
    for (int i = 0; i < N; ++i) qt[i] = (i == t) ? 1.0f : 0.0f;

    float betaS = 0.f, v0S = 0.f, alS = 0.f;  // lane k stashes beta_k / v0_k / alpha_k

    for (int iter = 0; iter < MAX_ITER; ++iter) {
        // ================= Phase 1: Householder QR, fused register passes =================
        float dotA, dotQ, wA, wQ;
        {   // prologue: deferred dot for k=0 (raw coefficient x0 at i=0), w = row 0
            float dA0 = 0.f, dA1 = 0.f, dQ0 = 0.f, dQ1 = 0.f;
            #pragma unroll
            for (int i = 0; i < N; ++i) {
                const float c = rl(a[i], 0);
                if (i & 1) { dA1 = fmaf(c, a[i], dA1); dQ1 = fmaf(c, qt[i], dQ1); }
                else       { dA0 = fmaf(c, a[i], dA0); dQ0 = fmaf(c, qt[i], dQ0); }
            }
            dotA = dA0 + dA1; dotQ = dQ0 + dQ1;
            wA = a[0]; wQ = qt[0];
        }

        #pragma unroll
        for (int kb = 0; kb < 8; ++kb) {
            const int dkEnd = (kb == 7) ? 7 : 8;          // k stops at 62
            for (int dk = 0; dk < dkEnd; ++dk) {
                const int k = 8 * kb + dk;
                const int k1 = k + 1;
                const float ss = rl(dotA, k);             // tail norm ||A[k:,k]||^2
                const float x0 = rl(wA, k);               // A[k][k]
                const float nrm = sqrtf(ss);
                const float alpha = (x0 >= 0.f) ? -nrm : nrm;
                const float v0 = x0 - alpha;
                const float vtv = fmaf(v0, v0, ss - x0 * x0);
                const float beta = (vtv > 1e-30f) ? __fdividef(2.0f, vtv) : 0.f;
                const float ca = beta * fmaf(-alpha, wA, dotA);   // deferred-coef fix
                const float cq = beta * fmaf(-alpha, wQ, dotQ);
                const float caE = (t > k) ? ca : 0.f;     // freeze columns <= k
                betaS = (t == k) ? beta  : betaS;
                v0S   = (t == k) ? v0    : v0S;
                alS   = (t == k) ? alpha : alS;

                float nA0 = 0.f, nA1 = 0.f, nQ0 = 0.f, nQ1 = 0.f, nwA = 0.f, nwQ = 0.f;
                #pragma unroll
                for (int i0 = 8 * kb; i0 < N; i0 += 8) {  // compile-time range per kb
                    #pragma unroll
                    for (int u = 0; u < 8; ++u) {
                        const int i = i0 + u;
                        float cu = rl(a[i], k);           // v_k[i] from lane k
                        if (i0 == 8 * kb) cu = (i > k) ? cu : ((i == k) ? v0 : 0.f);
                        a[i]  = fmaf(-caE, cu, a[i]);
                        qt[i] = fmaf(-cq,  cu, qt[i]);
                        float c2 = rl(a[i], k1);          // post-update col k+1 (raw)
                        if (i0 == 8 * kb) c2 = (i > k) ? c2 : 0.f;
                        if (u & 1) { nA1 = fmaf(c2, a[i], nA1); nQ1 = fmaf(c2, qt[i], nQ1); }
                        else       { nA0 = fmaf(c2, a[i], nA0); nQ0 = fmaf(c2, qt[i], nQ0); }
                        if ((i0 == 8 * kb && u > 0) || (kb < 7 && i0 == 8 * kb + 8 && u == 0)) {
                            const bool e = (i == k1);
                            nwA = e ? a[i]  : nwA;
                            nwQ = e ? qt[i] : nwQ;
                        }
                    }
                }
                dotA = nA0 + nA1; dotQ = nQ0 + nQ1; wA = nwA; wQ = nwQ;
            }
        }

        // ====== Archive columns -> G rows (plain, full — R region included) ======
        const float diagR = (t == N - 1) ? a[N - 1] : alS;  // R's diagonal (regs)
        #pragma unroll
        for (int j = 0; j < N; j += 4) {
            float4 w; w.x = a[j]; w.y = a[j + 1]; w.z = a[j + 2]; w.w = a[j + 3];
            *reinterpret_cast<float4*>(&G[t * GS + j]) = w;
        }

        // ==== Init r = row t of R via column read (conflict-free at stride 68) ====
        #pragma unroll
        for (int j = 0; j < N; ++j) {
            const float g = G[j * GS + t];
            r[j] = (j > t) ? g : ((j == t) ? diagR : 0.f);
        }

        // ==== Clean: row t := exact v_t (R region dead now) — kills k-loop masks ====
        #pragma unroll
        for (int j = 0; j < N; j += 4) {
            float4 w;
            w.x = (j + 0 > t) ? a[j + 0] : 0.f;
            w.y = (j + 1 > t) ? a[j + 1] : 0.f;
            w.z = (j + 2 > t) ? a[j + 2] : 0.f;
            w.w = (j + 3 > t) ? a[j + 3] : 0.f;
            *reinterpret_cast<float4*>(&G[t * GS + j]) = w;
        }
        G[t * GS + t] = v0S;                              // diag of row t = v0_t

        // ==== dR prologue: row 0 (= exact v_0) dot r ====
        float dR;
        {
            float d0 = 0.f, d1 = 0.f;
            #pragma unroll
            for (int j = 0; j < N; j += 4) {
                const float4 v = *reinterpret_cast<const float4*>(&G[j]);
                d0 = fmaf(v.x, r[j],     d0);
                d1 = fmaf(v.y, r[j + 1], d1);
                d0 = fmaf(v.z, r[j + 2], d0);
                d1 = fmaf(v.w, r[j + 3], d1);
            }
            dR = d0 + d1;
        }

        // ===== k-loop: FULLY UNROLLED — k compile-time, ds_read offset:imm, no =====
        // ===== block predicates. Same ops, same order => bit-exact vs R7.      =====
        #pragma unroll
        for (int k = 0; k < N - 1; ++k) {
            const float cc = rl(betaS, k) * dR;
            float nD0 = 0.f, nD1 = 0.f;
            #pragma unroll
            for (int j0 = 0; j0 < N; j0 += 8) {
                if (j0 + 8 > k) {                         // compile-time predicate
                    #pragma unroll
                    for (int h = 0; h < 2; ++h) {
                        const int jc = j0 + 4 * h;
                        const float4 vk  = *reinterpret_cast<const float4*>(
                            &G[k * GS + jc]);             // constant LDS offset
                        const float4 vk1 = *reinterpret_cast<const float4*>(
                            &G[(k + 1) * GS + jc]);       // constant LDS offset
                        r[jc + 0] = fmaf(-cc, vk.x, r[jc + 0]); nD0 = fmaf(vk1.x, r[jc + 0], nD0);
                        r[jc + 1] = fmaf(-cc, vk.y, r[jc + 1]); nD1 = fmaf(vk1.y, r[jc + 1], nD1);
                        r[jc + 2] = fmaf(-cc, vk.z, r[jc + 2]); nD0 = fmaf(vk1.z, r[jc + 2], nD0);
                        r[jc + 3] = fmaf(-cc, vk.w, r[jc + 3]); nD1 = fmaf(vk1.w, r[jc + 3], nD1);
                    }
                }
            }
            dR = nD0 + nD1;
        }
        #pragma unroll
        for (int j = 0; j < N; ++j) a[j] = r[j];          // symmetric: rows -> next cols
    }

    // ======= Epilogue: sm = log(clip(diag)), w = sm .* U-row, X = w . U^T =======
    #pragma unroll
    for (int l = 0; l < N; ++l) {
        const float dl = rl(a[l], l);                     // A5[l][l]
        const float sml = __logf(fmaxf(dl, 1e-6f));
        a[l] = sml * qt[l];                               // w[l] = sm[l] * U[t][l]
    }
    #pragma unroll
    for (int l = 0; l < N; l += 4) {                      // U rows -> G
        float4 w; w.x = qt[l]; w.y = qt[l + 1]; w.z = qt[l + 2]; w.w = qt[l + 3];
        *reinterpret_cast<float4*>(&G[t * GS + l]) = w;
    }
    #pragma unroll 2
    for (int j = 0; j < N; ++j) {                         // X[t][j]; store [j][t] (symmetric)
        float e0 = 0.f, e1 = 0.f, e2 = 0.f, e3 = 0.f;
        #pragma unroll
        for (int l = 0; l < N; l += 4) {
            const float4 u4 = *reinterpret_cast<const float4*>(&G[j * GS + l]);
            e0 = fmaf(a[l + 0], u4.x, e0);
            e1 = fmaf(a[l + 1], u4.y, e1);
            e2 = fmaf(a[l + 2], u4.z, e2);
            e3 = fmaf(a[l + 3], u4.w, e3);
        }
        out[j * N + t] = (e0 + e1) + (e2 + e3);           // coalesced
    }
}

extern "C" void kernel_launch(void* const* d_in, const int* in_sizes, int n_in,
                              void* d_out, int out_size, void* d_ws, size_t ws_size,
                              hipStream_t stream) {
    const float* in = (const float*)d_in[0];
    float* out = (float*)d_out;
    const int batch = in_sizes[0] / (N * N);
    hipLaunchKernelGGL(logm_kernel, dim3(batch), dim3(64), 0, stream, in, out);
}